// Round 1
// baseline (457.582 us; speedup 1.0000x reference)
//
#include <hip/hip_runtime.h>
#include <hip/hip_bf16.h>

// Problem: B=4, L=2048, E=1024, H=16, HD=64.
// Key insight: reshape(B,H,L,HD) is a pure reinterpretation of the flat (B,L,E)
// buffer -> per-head (L,HD) blocks are contiguous. Output merge is standard.
namespace {
constexpr int kB = 4, kL = 2048, kE = 1024, kH = 16, kHD = 64;
}

typedef __attribute__((ext_vector_type(8))) short bf16x8;
typedef __attribute__((ext_vector_type(4))) float f32x4;

__device__ __forceinline__ short f2bf(float f) {
  __hip_bfloat16 h = __float2bfloat16(f);
  return *reinterpret_cast<short*>(&h);
}

__device__ __forceinline__ void load_lds16(const void* g, void* l) {
  __builtin_amdgcn_global_load_lds((const __attribute__((address_space(1))) void*)g,
                                   (__attribute__((address_space(3))) void*)l, 16, 0, 0);
}

// fp32 -> bf16 cast, 4 elems/thread
__global__ __launch_bounds__(256) void k_cvt(const float* __restrict__ s,
                                             short* __restrict__ d, int n) {
  int i = (blockIdx.x * 256 + threadIdx.x) * 4;
  if (i < n) {
    float4 v = *reinterpret_cast<const float4*>(s + i);
    short4 o;
    o.x = f2bf(v.x); o.y = f2bf(v.y); o.z = f2bf(v.z); o.w = f2bf(v.w);
    *reinterpret_cast<short4*>(d + i) = o;
  }
}

// C(8192x1024) = A(8192x1024) . W(1024x1024)^T + bias   (NT GEMM, all bf16 in)
// mode 0: bf16 row-major out; mode 1: bf16 scattered per-head V-transpose out;
// mode 2: fp32 row-major out.
// LDS tiles use k-major chunk-plane layout: slot ci=(kc*ROWS+r), so frag
// ds_read_b128 banks = (row*4+dw)%32 -> 2-way alias only (free per m136).
__global__ __launch_bounds__(256) void k_gemm_nt(const short* __restrict__ A,
                                                 const short* __restrict__ W,
                                                 const float* __restrict__ bias,
                                                 void* __restrict__ outp, int mode) {
  __shared__ short As[4096];  // 128 rows x 32 k, planes of 128x8
  __shared__ short Bs[4096];
  const int K = 1024;
  const int tid = threadIdx.x;
  const int w = tid >> 6, lane = tid & 63;
  const int quad = lane >> 4, m16 = lane & 15;
  const int bn0 = blockIdx.x * 128, bm0 = blockIdx.y * 128;
  const int wm = (w >> 1) * 64, wn = (w & 1) * 64;
  const int r0 = tid & 127, kc0 = tid >> 7;  // staging slot -> (row, k-chunk)

  f32x4 acc[4][4] = {};

  const short* Arow = A + (bm0 + r0) * K + kc0 * 8;
  const short* Wrow = W + (bn0 + r0) * K + kc0 * 8;
  short* As0 = &As[tid * 8]; short* As1 = &As[(256 + tid) * 8];
  short* Bs0 = &Bs[tid * 8]; short* Bs1 = &Bs[(256 + tid) * 8];

  for (int kt = 0; kt < K; kt += 32) {
    load_lds16(Arow + kt, As0);
    load_lds16(Arow + kt + 16, As1);  // slot 256+tid -> kc=kc0+2 -> +16 elems
    load_lds16(Wrow + kt, Bs0);
    load_lds16(Wrow + kt + 16, Bs1);
    __syncthreads();
    bf16x8 a[4], b[4];
#pragma unroll
    for (int i = 0; i < 4; ++i)
      a[i] = *reinterpret_cast<const bf16x8*>(&As[quad * 1024 + (wm + i * 16 + m16) * 8]);
#pragma unroll
    for (int j = 0; j < 4; ++j)
      b[j] = *reinterpret_cast<const bf16x8*>(&Bs[quad * 1024 + (wn + j * 16 + m16) * 8]);
#pragma unroll
    for (int i = 0; i < 4; ++i)
#pragma unroll
      for (int j = 0; j < 4; ++j)
        acc[i][j] = __builtin_amdgcn_mfma_f32_16x16x32_bf16(a[i], b[j], acc[i][j], 0, 0, 0);
    __syncthreads();
  }

  float bj[4];
#pragma unroll
  for (int j = 0; j < 4; ++j) bj[j] = bias[bn0 + wn + j * 16 + m16];

  if (mode == 2) {
    float* C = reinterpret_cast<float*>(outp);
#pragma unroll
    for (int i = 0; i < 4; ++i)
#pragma unroll
      for (int j = 0; j < 4; ++j)
#pragma unroll
        for (int rg = 0; rg < 4; ++rg) {
          int row = bm0 + wm + i * 16 + quad * 4 + rg;
          int col = bn0 + wn + j * 16 + m16;
          C[row * 1024 + col] = acc[i][j][rg] + bj[j];
        }
  } else if (mode == 1) {
    // V epilogue: write transposed per-head layout Vt[hb][d][l].
    // flat elem (row,col): hb=row>>7, l=(row&127)*16+(col>>6), d=col&63
    short* C = reinterpret_cast<short*>(outp);
#pragma unroll
    for (int i = 0; i < 4; ++i)
#pragma unroll
      for (int j = 0; j < 4; ++j)
#pragma unroll
        for (int rg = 0; rg < 4; ++rg) {
          int row = bm0 + wm + i * 16 + quad * 4 + rg;
          int col = bn0 + wn + j * 16 + m16;
          int hb = row >> 7;
          int l = (row & 127) * 16 + (col >> 6);
          int d = col & 63;
          C[hb * 131072 + d * 2048 + l] = f2bf(acc[i][j][rg] + bj[j]);
        }
  } else {
    short* C = reinterpret_cast<short*>(outp);
#pragma unroll
    for (int i = 0; i < 4; ++i)
#pragma unroll
      for (int j = 0; j < 4; ++j)
#pragma unroll
        for (int rg = 0; rg < 4; ++rg) {
          int row = bm0 + wm + i * 16 + quad * 4 + rg;
          int col = bn0 + wn + j * 16 + m16;
          C[row * 1024 + col] = f2bf(acc[i][j][rg] + bj[j]);
        }
  }
}

// Flash-style attention, static-offset softmax (no running max needed:
// |logit| <= ||q||*||k||/8 ~ 15, so exp2(s*log2e/8 - 10) cannot overflow).
// Block: 128 q-rows of one head; 4 waves x 32 q-rows; K-blocks of 64 keys.
__global__ __launch_bounds__(256) void k_attn(const short* __restrict__ Q,
                                              const short* __restrict__ Km,
                                              const short* __restrict__ Vt,
                                              const int* __restrict__ mask,
                                              short* __restrict__ Out) {
  __shared__ short Qs[8192];   // 128x64, k-major planes (8 x 128 x 8)
  __shared__ short Ks[4096];   // 64x64, planes (8 x 64 x 8)
  __shared__ short Vs[4096];   // Vt block: rows=d, cols=keys, planes (8 x 64 x 8)
  __shared__ short Ps[8448];   // per-wave 8 planes x (32*8 + 8 pad) shorts
  __shared__ float mk[64];

  const int tid = threadIdx.x;
  const int w = tid >> 6, lane = tid & 63;
  const int quad = lane >> 4, m16 = lane & 15;
  const int qb = blockIdx.x, hb = blockIdx.y;
  const int b = hb >> 4, h = hb & 15;
  const int wb = w * 2112;

  const short* Qh = Q + hb * (kL * kHD) + qb * 128 * kHD;
  const short* Kh = Km + hb * (kL * kHD);
  const short* Vh = Vt + hb * (kL * kHD);

#pragma unroll
  for (int p = 0; p < 4; ++p) {
    int ci = p * 256 + tid;
    int r = ci & 127, kc = ci >> 7;
    load_lds16(Qh + r * 64 + kc * 8, &Qs[ci * 8]);
  }
  __syncthreads();
  bf16x8 qf[2][2];
#pragma unroll
  for (int i = 0; i < 2; ++i)
#pragma unroll
    for (int s = 0; s < 2; ++s)
      qf[i][s] = *reinterpret_cast<const bf16x8*>(
          &Qs[(s * 4 + quad) * 1024 + (w * 32 + i * 16 + m16) * 8]);

  f32x4 oacc[2][4] = {};
  float lpart[2][4] = {{0, 0, 0, 0}, {0, 0, 0, 0}};
  const float Cs = 0.18033688f;  // log2(e)/8

  const int r6 = tid & 63, kc6 = tid >> 6;
  for (int kb = 0; kb < 32; ++kb) {
    int kbase = kb * 64;
    load_lds16(Kh + (kbase + r6) * 64 + kc6 * 8, &Ks[tid * 8]);
    load_lds16(Kh + (kbase + r6) * 64 + (kc6 + 4) * 8, &Ks[(256 + tid) * 8]);
    load_lds16(Vh + r6 * 2048 + kbase + kc6 * 8, &Vs[tid * 8]);
    load_lds16(Vh + r6 * 2048 + kbase + (kc6 + 4) * 8, &Vs[(256 + tid) * 8]);
    if (tid < 64)
      mk[tid] = (mask[b * kL + kbase + tid] != 0) ? -10.0f : -1.4426951e10f;
    __syncthreads();

    bf16x8 kf[4][2];
#pragma unroll
    for (int j = 0; j < 4; ++j)
#pragma unroll
      for (int s = 0; s < 2; ++s)
        kf[j][s] = *reinterpret_cast<const bf16x8*>(
            &Ks[(s * 4 + quad) * 512 + (j * 16 + m16) * 8]);

    f32x4 S[2][4] = {};
#pragma unroll
    for (int i = 0; i < 2; ++i)
#pragma unroll
      for (int j = 0; j < 4; ++j) {
        S[i][j] = __builtin_amdgcn_mfma_f32_16x16x32_bf16(qf[i][0], kf[j][0], S[i][j], 0, 0, 0);
        S[i][j] = __builtin_amdgcn_mfma_f32_16x16x32_bf16(qf[i][1], kf[j][1], S[i][j], 0, 0, 0);
      }

    float mj[4];
#pragma unroll
    for (int j = 0; j < 4; ++j) mj[j] = mk[j * 16 + m16];

#pragma unroll
    for (int i = 0; i < 2; ++i) {
      int prow_base = i * 16 + quad * 4;
#pragma unroll
      for (int j = 0; j < 4; ++j) {
        int col = j * 16 + m16;
        int cidx = wb + (col >> 3) * 264 + (col & 7);
#pragma unroll
        for (int rg = 0; rg < 4; ++rg) {
          float p = exp2f(S[i][j][rg] * Cs + mj[j]);
          lpart[i][rg] += p;
          Ps[cidx + (prow_base + rg) * 8] = f2bf(p);
        }
      }
    }
    asm volatile("s_waitcnt lgkmcnt(0)" ::: "memory");  // own-wave P RAW

    bf16x8 pf[2][2], vf[4][2];
#pragma unroll
    for (int i = 0; i < 2; ++i)
#pragma unroll
      for (int s = 0; s < 2; ++s)
        pf[i][s] = *reinterpret_cast<const bf16x8*>(
            &Ps[wb + (s * 4 + quad) * 264 + (i * 16 + m16) * 8]);
#pragma unroll
    for (int j = 0; j < 4; ++j)
#pragma unroll
      for (int s = 0; s < 2; ++s)
        vf[j][s] = *reinterpret_cast<const bf16x8*>(
            &Vs[(s * 4 + quad) * 512 + (j * 16 + m16) * 8]);
#pragma unroll
    for (int i = 0; i < 2; ++i)
#pragma unroll
      for (int j = 0; j < 4; ++j) {
        oacc[i][j] = __builtin_amdgcn_mfma_f32_16x16x32_bf16(pf[i][0], vf[j][0], oacc[i][j], 0, 0, 0);
        oacc[i][j] = __builtin_amdgcn_mfma_f32_16x16x32_bf16(pf[i][1], vf[j][1], oacc[i][j], 0, 0, 0);
      }
    __syncthreads();
  }

  float linv[2][4];
#pragma unroll
  for (int i = 0; i < 2; ++i)
#pragma unroll
    for (int rg = 0; rg < 4; ++rg) {
      float l = lpart[i][rg];
      l += __shfl_xor(l, 1);
      l += __shfl_xor(l, 2);
      l += __shfl_xor(l, 4);
      l += __shfl_xor(l, 8);
      linv[i][rg] = 1.0f / l;
    }

#pragma unroll
  for (int i = 0; i < 2; ++i)
#pragma unroll
    for (int j = 0; j < 4; ++j) {
      int d = j * 16 + m16;
#pragma unroll
      for (int rg = 0; rg < 4; ++rg) {
        int ql = qb * 128 + w * 32 + i * 16 + quad * 4 + rg;
        Out[(b * kL + ql) * kE + h * kHD + d] = f2bf(oacc[i][j][rg] * linv[i][rg]);
      }
    }
}

extern "C" void kernel_launch(void* const* d_in, const int* in_sizes, int n_in,
                              void* d_out, int out_size, void* d_ws, size_t ws_size,
                              hipStream_t stream) {
  const float* x  = (const float*)d_in[0];
  const int* mask = (const int*)d_in[1];
  const float* Wq = (const float*)d_in[2];
  const float* bq = (const float*)d_in[3];
  const float* Wk = (const float*)d_in[4];
  const float* bk = (const float*)d_in[5];
  const float* Wv = (const float*)d_in[6];
  const float* bv = (const float*)d_in[7];
  const float* Wo = (const float*)d_in[8];
  const float* bo = (const float*)d_in[9];

  short* ws  = (short*)d_ws;        // total use: ~92.3 MB
  short* xb  = ws;                  // 8388608 shorts
  short* Wqb = xb  + 8388608;       // 1048576 each
  short* Wkb = Wqb + 1048576;
  short* Wvb = Wkb + 1048576;
  short* Wob = Wvb + 1048576;
  short* Qb  = Wob + 1048576;       // 8388608 each
  short* Kb  = Qb  + 8388608;
  short* Vtb = Kb  + 8388608;
  short* AOb = Vtb + 8388608;

  k_cvt<<<8192, 256, 0, stream>>>(x, xb, 8388608);
  k_cvt<<<1024, 256, 0, stream>>>(Wq, Wqb, 1048576);
  k_cvt<<<1024, 256, 0, stream>>>(Wk, Wkb, 1048576);
  k_cvt<<<1024, 256, 0, stream>>>(Wv, Wvb, 1048576);
  k_cvt<<<1024, 256, 0, stream>>>(Wo, Wob, 1048576);

  dim3 g(8, 64), blk(256);
  k_gemm_nt<<<g, blk, 0, stream>>>(xb, Wqb, bq, Qb, 0);
  k_gemm_nt<<<g, blk, 0, stream>>>(xb, Wkb, bk, Kb, 0);
  k_gemm_nt<<<g, blk, 0, stream>>>(xb, Wvb, bv, Vtb, 1);
  k_attn<<<dim3(16, 64), blk, 0, stream>>>(Qb, Kb, Vtb, mask, AOb);
  k_gemm_nt<<<g, blk, 0, stream>>>(AOb, Wob, bo, d_out, 2);
}

// Round 2
// 414.380 us; speedup vs baseline: 1.1043x; 1.1043x over previous
//
#include <hip/hip_runtime.h>
#include <hip/hip_bf16.h>

// Problem: B=4, L=2048, E=1024, H=16, HD=64.
// reshape(B,H,L,HD) is a pure reinterpretation of the flat (B,L,E) buffer.
namespace {
constexpr int kB = 4, kL = 2048, kE = 1024, kH = 16, kHD = 64;
constexpr float kCs = 0.18033688f;  // log2(e)/8, folded into Q projection
}

typedef __attribute__((ext_vector_type(8))) short bf16x8;
typedef __attribute__((ext_vector_type(4))) float f32x4;

__device__ __forceinline__ short f2bf(float f) {
  __hip_bfloat16 h = __float2bfloat16(f);
  return *reinterpret_cast<short*>(&h);
}

__device__ __forceinline__ void load_lds16(const void* g, void* l) {
  __builtin_amdgcn_global_load_lds((const __attribute__((address_space(1))) void*)g,
                                   (__attribute__((address_space(3))) void*)l, 16, 0, 0);
}

// fp32 -> bf16 cast, 4 elems/thread
__global__ __launch_bounds__(256) void k_cvt(const float* __restrict__ s,
                                             short* __restrict__ d, int n) {
  int i = (blockIdx.x * 256 + threadIdx.x) * 4;
  if (i < n) {
    float4 v = *reinterpret_cast<const float4*>(s + i);
    short4 o;
    o.x = f2bf(v.x); o.y = f2bf(v.y); o.z = f2bf(v.z); o.w = f2bf(v.w);
    *reinterpret_cast<short4*>(d + i) = o;
  }
}

// All 4 weight casts in one dispatch. Dst buffers are contiguous at dst.
__global__ __launch_bounds__(256) void k_cvtw(const float* __restrict__ w0,
                                              const float* __restrict__ w1,
                                              const float* __restrict__ w2,
                                              const float* __restrict__ w3,
                                              short* __restrict__ dst) {
  int seg = blockIdx.x >> 10;
  const float* s = seg == 0 ? w0 : seg == 1 ? w1 : seg == 2 ? w2 : w3;
  int local = ((blockIdx.x & 1023) * 256 + threadIdx.x) * 4;
  float4 v = *reinterpret_cast<const float4*>(s + local);
  short4 o;
  o.x = f2bf(v.x); o.y = f2bf(v.y); o.z = f2bf(v.z); o.w = f2bf(v.w);
  *reinterpret_cast<short4*>(dst + seg * 1048576 + local) = o;
}

// ---- shared GEMM core: 128x128 tile, BK=32, NT, k-major chunk-plane LDS ----
struct GemmCore {
  f32x4 acc[4][4];
  int tid, w, lane, quad, m16, wm, wn, r0, kc0;
  __device__ __forceinline__ void run(const short* __restrict__ A,
                                      const short* __restrict__ W,
                                      int bm0, int bn0, short* As, short* Bs) {
    const int K = 1024;
    tid = threadIdx.x;
    w = tid >> 6; lane = tid & 63; quad = lane >> 4; m16 = lane & 15;
    wm = (w >> 1) * 64; wn = (w & 1) * 64;
    r0 = tid & 127; kc0 = tid >> 7;
#pragma unroll
    for (int i = 0; i < 4; ++i)
#pragma unroll
      for (int j = 0; j < 4; ++j) acc[i][j] = (f32x4){0, 0, 0, 0};
    const short* Arow = A + (bm0 + r0) * K + kc0 * 8;
    const short* Wrow = W + (bn0 + r0) * K + kc0 * 8;
    short* As0 = &As[tid * 8]; short* As1 = &As[(256 + tid) * 8];
    short* Bs0 = &Bs[tid * 8]; short* Bs1 = &Bs[(256 + tid) * 8];
    for (int kt = 0; kt < K; kt += 32) {
      load_lds16(Arow + kt, As0);
      load_lds16(Arow + kt + 16, As1);
      load_lds16(Wrow + kt, Bs0);
      load_lds16(Wrow + kt + 16, Bs1);
      __syncthreads();
      bf16x8 a[4], b[4];
#pragma unroll
      for (int i = 0; i < 4; ++i)
        a[i] = *reinterpret_cast<const bf16x8*>(&As[quad * 1024 + (wm + i * 16 + m16) * 8]);
#pragma unroll
      for (int j = 0; j < 4; ++j)
        b[j] = *reinterpret_cast<const bf16x8*>(&Bs[quad * 1024 + (wn + j * 16 + m16) * 8]);
#pragma unroll
      for (int i = 0; i < 4; ++i)
#pragma unroll
        for (int j = 0; j < 4; ++j)
          acc[i][j] = __builtin_amdgcn_mfma_f32_16x16x32_bf16(a[i], b[j], acc[i][j], 0, 0, 0);
      __syncthreads();
    }
  }
};

// Fused Q/K/V projection: grid.x = 24 (8 col-blocks x 3 outputs).
// Q: bf16 row-major, pre-scaled by log2(e)/8. K: bf16 row-major.
// V: bf16 scattered per-head transpose Vt[hb][d][l].
__global__ __launch_bounds__(256) void k_gemm_qkv(const short* __restrict__ xb,
                                                  const short* __restrict__ Wq,
                                                  const short* __restrict__ Wk,
                                                  const short* __restrict__ Wv,
                                                  const float* __restrict__ bq,
                                                  const float* __restrict__ bk,
                                                  const float* __restrict__ bv,
                                                  short* __restrict__ Q,
                                                  short* __restrict__ K,
                                                  short* __restrict__ Vt) {
  __shared__ short As[4096];
  __shared__ short Bs[4096];
  const int sel = blockIdx.x >> 3;
  const int bn0 = (blockIdx.x & 7) * 128, bm0 = blockIdx.y * 128;
  const short* W = sel == 0 ? Wq : sel == 1 ? Wk : Wv;
  const float* bias = sel == 0 ? bq : sel == 1 ? bk : bv;

  GemmCore g;
  g.run(xb, W, bm0, bn0, As, Bs);

  float bj[4];
#pragma unroll
  for (int j = 0; j < 4; ++j) bj[j] = bias[bn0 + g.wn + j * 16 + g.m16];

  if (sel == 2) {
    // V: write transposed per-head layout Vt[hb][d][l]
#pragma unroll
    for (int i = 0; i < 4; ++i)
#pragma unroll
      for (int j = 0; j < 4; ++j)
#pragma unroll
        for (int rg = 0; rg < 4; ++rg) {
          int row = bm0 + g.wm + i * 16 + g.quad * 4 + rg;
          int col = bn0 + g.wn + j * 16 + g.m16;
          int hb = row >> 7;
          int l = (row & 127) * 16 + (col >> 6);
          int d = col & 63;
          Vt[hb * 131072 + d * 2048 + l] = f2bf(g.acc[i][j][rg] + bj[j]);
        }
  } else {
    short* C = sel == 0 ? Q : K;
    float sc = sel == 0 ? kCs : 1.0f;
#pragma unroll
    for (int i = 0; i < 4; ++i)
#pragma unroll
      for (int j = 0; j < 4; ++j)
#pragma unroll
        for (int rg = 0; rg < 4; ++rg) {
          int row = bm0 + g.wm + i * 16 + g.quad * 4 + rg;
          int col = bn0 + g.wn + j * 16 + g.m16;
          C[row * 1024 + col] = f2bf((g.acc[i][j][rg] + bj[j]) * sc);
        }
  }
}

// Output projection: fp32 row-major out.
__global__ __launch_bounds__(256) void k_gemm_out(const short* __restrict__ A,
                                                  const short* __restrict__ Wo,
                                                  const float* __restrict__ bo,
                                                  float* __restrict__ C) {
  __shared__ short As[4096];
  __shared__ short Bs[4096];
  const int bn0 = blockIdx.x * 128, bm0 = blockIdx.y * 128;
  GemmCore g;
  g.run(A, Wo, bm0, bn0, As, Bs);
  float bj[4];
#pragma unroll
  for (int j = 0; j < 4; ++j) bj[j] = bo[bn0 + g.wn + j * 16 + g.m16];
#pragma unroll
  for (int i = 0; i < 4; ++i)
#pragma unroll
    for (int j = 0; j < 4; ++j)
#pragma unroll
      for (int rg = 0; rg < 4; ++rg) {
        int row = bm0 + g.wm + i * 16 + g.quad * 4 + rg;
        int col = bn0 + g.wn + j * 16 + g.m16;
        C[row * 1024 + col] = g.acc[i][j][rg] + bj[j];
      }
}

// Flash-style attention, S^T formulation.
// Q pre-scaled by log2(e)/8; mask offset folded into MFMA acc init, so the
// softmax inner body is exp2 + round-add + perm-pack + ds_write_b64.
// S^T = K.Q^T (mfma(kf,qf)): C col = q = lane&15, row = key = quad*4+rg ->
// each lane holds 4 CONTIGUOUS keys of one q-row = fast axis of P's A-layout.
__global__ __launch_bounds__(256) void k_attn(const short* __restrict__ Q,
                                              const short* __restrict__ Km,
                                              const short* __restrict__ Vt,
                                              const int* __restrict__ mask,
                                              short* __restrict__ Out) {
  __shared__ __attribute__((aligned(16))) short Qs[8192];  // 128x64, k-major planes
  __shared__ __attribute__((aligned(16))) short Ks[4096];  // 64x64, planes
  __shared__ __attribute__((aligned(16))) short Vs[4096];  // Vt: rows=d, cols=keys
  __shared__ __attribute__((aligned(16))) short Ps[8448];  // per-wave 8 planes x (32*8+8)
  __shared__ __attribute__((aligned(16))) float mk[64];

  const int tid = threadIdx.x;
  const int w = tid >> 6, lane = tid & 63;
  const int quad = lane >> 4, m16 = lane & 15;
  const int qb = blockIdx.x, hb = blockIdx.y;
  const int b = hb >> 4, h = hb & 15;
  const int wb = w * 2112;

  const short* Qh = Q + hb * (kL * kHD) + qb * 128 * kHD;
  const short* Kh = Km + hb * (kL * kHD);
  const short* Vh = Vt + hb * (kL * kHD);

#pragma unroll
  for (int p = 0; p < 4; ++p) {
    int ci = p * 256 + tid;
    int r = ci & 127, kc = ci >> 7;
    load_lds16(Qh + r * 64 + kc * 8, &Qs[ci * 8]);
  }
  __syncthreads();
  bf16x8 qf[2][2];
#pragma unroll
  for (int i = 0; i < 2; ++i)
#pragma unroll
    for (int s = 0; s < 2; ++s)
      qf[i][s] = *reinterpret_cast<const bf16x8*>(
          &Qs[(s * 4 + quad) * 1024 + (w * 32 + i * 16 + m16) * 8]);

  f32x4 oacc[2][4] = {};
  float lpart[2][4] = {{0, 0, 0, 0}, {0, 0, 0, 0}};

  const int r6 = tid & 63, kc6 = tid >> 6;
  for (int kb = 0; kb < 32; ++kb) {
    int kbase = kb * 64;
    load_lds16(Kh + (kbase + r6) * 64 + kc6 * 8, &Ks[tid * 8]);
    load_lds16(Kh + (kbase + r6) * 64 + (kc6 + 4) * 8, &Ks[(256 + tid) * 8]);
    load_lds16(Vh + r6 * 2048 + kbase + kc6 * 8, &Vs[tid * 8]);
    load_lds16(Vh + r6 * 2048 + kbase + (kc6 + 4) * 8, &Vs[(256 + tid) * 8]);
    if (tid < 64)
      mk[tid] = (mask[b * kL + kbase + tid] != 0) ? -10.0f : -1.0e10f;
    __syncthreads();

    bf16x8 kf[4][2];
#pragma unroll
    for (int j = 0; j < 4; ++j)
#pragma unroll
      for (int s = 0; s < 2; ++s)
        kf[j][s] = *reinterpret_cast<const bf16x8*>(
            &Ks[(s * 4 + quad) * 512 + (j * 16 + m16) * 8]);

    // S^T tiles: ST[j][i], j = key-tile (rows), i = q-tile (cols).
    // Init with mask offset (per-row = per-key broadcast float4 from mk).
    f32x4 ST[4][2];
#pragma unroll
    for (int j = 0; j < 4; ++j) {
      float4 mj4 = *reinterpret_cast<const float4*>(&mk[j * 16 + quad * 4]);
      f32x4 init; init[0] = mj4.x; init[1] = mj4.y; init[2] = mj4.z; init[3] = mj4.w;
#pragma unroll
      for (int i = 0; i < 2; ++i) ST[j][i] = init;
    }
#pragma unroll
    for (int j = 0; j < 4; ++j)
#pragma unroll
      for (int i = 0; i < 2; ++i) {
        ST[j][i] = __builtin_amdgcn_mfma_f32_16x16x32_bf16(kf[j][0], qf[i][0], ST[j][i], 0, 0, 0);
        ST[j][i] = __builtin_amdgcn_mfma_f32_16x16x32_bf16(kf[j][1], qf[i][1], ST[j][i], 0, 0, 0);
      }

    // Softmax numerator + pack to bf16 + b64 spill into P (A-operand layout).
    const int kc_w = (quad >> 1);   // within j: plane = j*2 + (quad>>1)
    const int inner = (quad & 1) * 4;
#pragma unroll
    for (int j = 0; j < 4; ++j)
#pragma unroll
      for (int i = 0; i < 2; ++i) {
        float p0 = __builtin_amdgcn_exp2f(ST[j][i][0]);
        float p1 = __builtin_amdgcn_exp2f(ST[j][i][1]);
        float p2 = __builtin_amdgcn_exp2f(ST[j][i][2]);
        float p3 = __builtin_amdgcn_exp2f(ST[j][i][3]);
        lpart[i][0] += p0; lpart[i][1] += p1;
        lpart[i][2] += p2; lpart[i][3] += p3;
        unsigned u0 = __builtin_bit_cast(unsigned, p0) + 0x8000u;
        unsigned u1 = __builtin_bit_cast(unsigned, p1) + 0x8000u;
        unsigned u2 = __builtin_bit_cast(unsigned, p2) + 0x8000u;
        unsigned u3 = __builtin_bit_cast(unsigned, p3) + 0x8000u;
        uint2 pk;
        pk.x = __builtin_amdgcn_perm(u1, u0, 0x07060302u);
        pk.y = __builtin_amdgcn_perm(u3, u2, 0x07060302u);
        *reinterpret_cast<uint2*>(
            &Ps[wb + (j * 2 + kc_w) * 264 + (i * 16 + m16) * 8 + inner]) = pk;
      }
    asm volatile("s_waitcnt lgkmcnt(0)" ::: "memory");  // own-wave P RAW

    bf16x8 pf[2][2], vf[4][2];
#pragma unroll
    for (int i = 0; i < 2; ++i)
#pragma unroll
      for (int s = 0; s < 2; ++s)
        pf[i][s] = *reinterpret_cast<const bf16x8*>(
            &Ps[wb + (s * 4 + quad) * 264 + (i * 16 + m16) * 8]);
#pragma unroll
    for (int j = 0; j < 4; ++j)
#pragma unroll
      for (int s = 0; s < 2; ++s)
        vf[j][s] = *reinterpret_cast<const bf16x8*>(
            &Vs[(s * 4 + quad) * 512 + (j * 16 + m16) * 8]);
#pragma unroll
    for (int i = 0; i < 2; ++i)
#pragma unroll
      for (int j = 0; j < 4; ++j) {
        oacc[i][j] = __builtin_amdgcn_mfma_f32_16x16x32_bf16(pf[i][0], vf[j][0], oacc[i][j], 0, 0, 0);
        oacc[i][j] = __builtin_amdgcn_mfma_f32_16x16x32_bf16(pf[i][1], vf[j][1], oacc[i][j], 0, 0, 0);
      }
    __syncthreads();
  }

  // l reduce: lane holds partials for q = i*16+m16 over keys {quad's 16}.
  float linv[2][4];
#pragma unroll
  for (int i = 0; i < 2; ++i) {
    float l = lpart[i][0] + lpart[i][1] + lpart[i][2] + lpart[i][3];
    l += __shfl_xor(l, 16);
    l += __shfl_xor(l, 32);  // now full l(q = i*16+m16)
#pragma unroll
    for (int rg = 0; rg < 4; ++rg)
      linv[i][rg] = 1.0f / __shfl(l, quad * 4 + rg);
  }

#pragma unroll
  for (int i = 0; i < 2; ++i)
#pragma unroll
    for (int j = 0; j < 4; ++j) {
      int d = j * 16 + m16;
#pragma unroll
      for (int rg = 0; rg < 4; ++rg) {
        int ql = qb * 128 + w * 32 + i * 16 + quad * 4 + rg;
        Out[(b * kL + ql) * kE + h * kHD + d] = f2bf(oacc[i][j][rg] * linv[i][rg]);
      }
    }
}

extern "C" void kernel_launch(void* const* d_in, const int* in_sizes, int n_in,
                              void* d_out, int out_size, void* d_ws, size_t ws_size,
                              hipStream_t stream) {
  const float* x  = (const float*)d_in[0];
  const int* mask = (const int*)d_in[1];
  const float* Wq = (const float*)d_in[2];
  const float* bq = (const float*)d_in[3];
  const float* Wk = (const float*)d_in[4];
  const float* bk = (const float*)d_in[5];
  const float* Wv = (const float*)d_in[6];
  const float* bv = (const float*)d_in[7];
  const float* Wo = (const float*)d_in[8];
  const float* bo = (const float*)d_in[9];

  short* ws  = (short*)d_ws;
  short* xb  = ws;                  // 8388608 shorts
  short* Wqb = xb  + 8388608;       // 4 x 1048576, contiguous
  short* Wkb = Wqb + 1048576;
  short* Wvb = Wkb + 1048576;
  short* Wob = Wvb + 1048576;
  short* Qb  = Wob + 1048576;       // 8388608 each
  short* Kb  = Qb  + 8388608;
  short* Vtb = Kb  + 8388608;
  short* AOb = Vtb + 8388608;

  k_cvt<<<8192, 256, 0, stream>>>(x, xb, 8388608);
  k_cvtw<<<4096, 256, 0, stream>>>(Wq, Wk, Wv, Wo, Wqb);

  k_gemm_qkv<<<dim3(24, 64), 256, 0, stream>>>(xb, Wqb, Wkb, Wvb, bq, bk, bv, Qb, Kb, Vtb);
  k_attn<<<dim3(16, 64), 256, 0, stream>>>(Qb, Kb, Vtb, mask, AOb);
  k_gemm_out<<<dim3(8, 64), 256, 0, stream>>>(AOb, Wob, bo, (float*)d_out);
}

// Round 3
// 374.052 us; speedup vs baseline: 1.2233x; 1.1078x over previous
//
#include <hip/hip_runtime.h>
#include <hip/hip_bf16.h>

// Problem: B=4, L=2048, E=1024, H=16, HD=64.
// reshape(B,H,L,HD) is a pure reinterpretation of the flat (B,L,E) buffer.
namespace {
constexpr int kB = 4, kL = 2048, kE = 1024, kH = 16, kHD = 64;
constexpr float kCs = 0.18033688f;  // log2(e)/8, folded into Q projection
}

typedef __attribute__((ext_vector_type(8))) short bf16x8;
typedef __attribute__((ext_vector_type(4))) float f32x4;

__device__ __forceinline__ short f2bf(float f) {
  __hip_bfloat16 h = __float2bfloat16(f);
  return *reinterpret_cast<short*>(&h);
}

__device__ __forceinline__ void load_lds16(const void* g, void* l) {
  __builtin_amdgcn_global_load_lds((const __attribute__((address_space(1))) void*)g,
                                   (__attribute__((address_space(3))) void*)l, 16, 0, 0);
}

// fp32 -> bf16 cast, 4 elems/thread
__global__ __launch_bounds__(256) void k_cvt(const float* __restrict__ s,
                                             short* __restrict__ d, int n) {
  int i = (blockIdx.x * 256 + threadIdx.x) * 4;
  if (i < n) {
    float4 v = *reinterpret_cast<const float4*>(s + i);
    short4 o;
    o.x = f2bf(v.x); o.y = f2bf(v.y); o.z = f2bf(v.z); o.w = f2bf(v.w);
    *reinterpret_cast<short4*>(d + i) = o;
  }
}

// All 4 weight casts in one dispatch. Dst buffers are contiguous at dst.
__global__ __launch_bounds__(256) void k_cvtw(const float* __restrict__ w0,
                                              const float* __restrict__ w1,
                                              const float* __restrict__ w2,
                                              const float* __restrict__ w3,
                                              short* __restrict__ dst) {
  int seg = blockIdx.x >> 10;
  const float* s = seg == 0 ? w0 : seg == 1 ? w1 : seg == 2 ? w2 : w3;
  int local = ((blockIdx.x & 1023) * 256 + threadIdx.x) * 4;
  float4 v = *reinterpret_cast<const float4*>(s + local);
  short4 o;
  o.x = f2bf(v.x); o.y = f2bf(v.y); o.z = f2bf(v.z); o.w = f2bf(v.w);
  *reinterpret_cast<short4*>(dst + seg * 1048576 + local) = o;
}

// Per-head V transpose: Vl[hb][l][d] -> Vt[hb][d][l]. 64x64 tiles via LDS,
// both global sides coalesced. Shorts paired into uints with v_perm so all
// LDS traffic is b32/b128; row pad 33 uints keeps banks ~2-way (free).
__global__ __launch_bounds__(256) void k_trv(const short* __restrict__ Vl,
                                             short* __restrict__ Vt) {
  __shared__ unsigned T[64 * 33];
  const int t = threadIdx.x;
  const int hb = blockIdx.y;
  const int l0 = blockIdx.x * 64;
  const short* src = Vl + hb * 131072;
  short* dst = Vt + hb * 131072;
  const int d8 = (t & 7) * 8;   // 8 lanes cover one 128B row chunk
  const int lp = t >> 3;        // row pair index 0..31 -> rows 2lp, 2lp+1
  const uint4 va = *reinterpret_cast<const uint4*>(src + (l0 + 2 * lp) * 64 + d8);
  const uint4 vb = *reinterpret_cast<const uint4*>(src + (l0 + 2 * lp + 1) * 64 + d8);
  const unsigned a[4] = {va.x, va.y, va.z, va.w};
  const unsigned b[4] = {vb.x, vb.y, vb.z, vb.w};
#pragma unroll
  for (int j = 0; j < 4; ++j) {
    // z0 = (V[2lp+1][d]<<16) | V[2lp][d]   for d = d8+2j, z1 for d8+2j+1
    unsigned z0 = __builtin_amdgcn_perm(b[j], a[j], 0x05040100u);
    unsigned z1 = __builtin_amdgcn_perm(b[j], a[j], 0x07060302u);
    T[(d8 + 2 * j) * 33 + lp] = z0;
    T[(d8 + 2 * j + 1) * 33 + lp] = z1;
  }
  __syncthreads();
  const int u = (t & 7) * 4;    // uint offset in d-row; 8 lanes = 128B line
#pragma unroll
  for (int h2 = 0; h2 < 2; ++h2) {
    int d = (t >> 3) + h2 * 32;
    uint4 r;
    r.x = T[d * 33 + u];     r.y = T[d * 33 + u + 1];
    r.z = T[d * 33 + u + 2]; r.w = T[d * 33 + u + 3];
    *reinterpret_cast<uint4*>(dst + d * 2048 + l0 + u * 2) = r;
  }
}

// ---- shared GEMM core: 128x128 tile, BK=32, NT, k-major chunk-plane LDS ----
struct GemmCore {
  f32x4 acc[4][4];
  int tid, w, lane, quad, m16, wm, wn, r0, kc0;
  __device__ __forceinline__ void run(const short* __restrict__ A,
                                      const short* __restrict__ W,
                                      int bm0, int bn0, short* As, short* Bs) {
    const int K = 1024;
    tid = threadIdx.x;
    w = tid >> 6; lane = tid & 63; quad = lane >> 4; m16 = lane & 15;
    wm = (w >> 1) * 64; wn = (w & 1) * 64;
    r0 = tid & 127; kc0 = tid >> 7;
#pragma unroll
    for (int i = 0; i < 4; ++i)
#pragma unroll
      for (int j = 0; j < 4; ++j) acc[i][j] = (f32x4){0, 0, 0, 0};
    const short* Arow = A + (bm0 + r0) * K + kc0 * 8;
    const short* Wrow = W + (bn0 + r0) * K + kc0 * 8;
    short* As0 = &As[tid * 8]; short* As1 = &As[(256 + tid) * 8];
    short* Bs0 = &Bs[tid * 8]; short* Bs1 = &Bs[(256 + tid) * 8];
    for (int kt = 0; kt < K; kt += 32) {
      load_lds16(Arow + kt, As0);
      load_lds16(Arow + kt + 16, As1);
      load_lds16(Wrow + kt, Bs0);
      load_lds16(Wrow + kt + 16, Bs1);
      __syncthreads();
      bf16x8 a[4], b[4];
#pragma unroll
      for (int i = 0; i < 4; ++i)
        a[i] = *reinterpret_cast<const bf16x8*>(&As[quad * 1024 + (wm + i * 16 + m16) * 8]);
#pragma unroll
      for (int j = 0; j < 4; ++j)
        b[j] = *reinterpret_cast<const bf16x8*>(&Bs[quad * 1024 + (wn + j * 16 + m16) * 8]);
#pragma unroll
      for (int i = 0; i < 4; ++i)
#pragma unroll
        for (int j = 0; j < 4; ++j)
          acc[i][j] = __builtin_amdgcn_mfma_f32_16x16x32_bf16(a[i], b[j], acc[i][j], 0, 0, 0);
      __syncthreads();
    }
  }
};

// Fused Q/K/V projection: grid.x = 24 (8 col-blocks x 3 outputs).
// Q: bf16 row-major, pre-scaled by log2(e)/8. K, V: bf16 row-major.
// (V's per-head transpose is done by k_trv — scattered 2B stores here caused
//  4.5x write amplification in R1.)
__global__ __launch_bounds__(256) void k_gemm_qkv(const short* __restrict__ xb,
                                                  const short* __restrict__ Wq,
                                                  const short* __restrict__ Wk,
                                                  const short* __restrict__ Wv,
                                                  const float* __restrict__ bq,
                                                  const float* __restrict__ bk,
                                                  const float* __restrict__ bv,
                                                  short* __restrict__ Q,
                                                  short* __restrict__ K,
                                                  short* __restrict__ Vl) {
  __shared__ short As[4096];
  __shared__ short Bs[4096];
  const int sel = blockIdx.x >> 3;
  const int bn0 = (blockIdx.x & 7) * 128, bm0 = blockIdx.y * 128;
  const short* W = sel == 0 ? Wq : sel == 1 ? Wk : Wv;
  const float* bias = sel == 0 ? bq : sel == 1 ? bk : bv;

  GemmCore g;
  g.run(xb, W, bm0, bn0, As, Bs);

  float bj[4];
#pragma unroll
  for (int j = 0; j < 4; ++j) bj[j] = bias[bn0 + g.wn + j * 16 + g.m16];

  short* C = sel == 0 ? Q : sel == 1 ? K : Vl;
  float sc = sel == 0 ? kCs : 1.0f;
#pragma unroll
  for (int i = 0; i < 4; ++i)
#pragma unroll
    for (int j = 0; j < 4; ++j)
#pragma unroll
      for (int rg = 0; rg < 4; ++rg) {
        int row = bm0 + g.wm + i * 16 + g.quad * 4 + rg;
        int col = bn0 + g.wn + j * 16 + g.m16;
        C[row * 1024 + col] = f2bf((g.acc[i][j][rg] + bj[j]) * sc);
      }
}

// Output projection: fp32 row-major out.
__global__ __launch_bounds__(256) void k_gemm_out(const short* __restrict__ A,
                                                  const short* __restrict__ Wo,
                                                  const float* __restrict__ bo,
                                                  float* __restrict__ C) {
  __shared__ short As[4096];
  __shared__ short Bs[4096];
  const int bn0 = blockIdx.x * 128, bm0 = blockIdx.y * 128;
  GemmCore g;
  g.run(A, Wo, bm0, bn0, As, Bs);
  float bj[4];
#pragma unroll
  for (int j = 0; j < 4; ++j) bj[j] = bo[bn0 + g.wn + j * 16 + g.m16];
#pragma unroll
  for (int i = 0; i < 4; ++i)
#pragma unroll
    for (int j = 0; j < 4; ++j)
#pragma unroll
      for (int rg = 0; rg < 4; ++rg) {
        int row = bm0 + g.wm + i * 16 + g.quad * 4 + rg;
        int col = bn0 + g.wn + j * 16 + g.m16;
        C[row * 1024 + col] = g.acc[i][j][rg] + bj[j];
      }
}

// Flash-style attention, S^T formulation.
// Q pre-scaled by log2(e)/8; mask offset folded into MFMA acc init, so the
// softmax inner body is exp2 + round-add + perm-pack + ds_write_b64.
// S^T = K.Q^T (mfma(kf,qf)): C col = q = lane&15, row = key = quad*4+rg ->
// each lane holds 4 CONTIGUOUS keys of one q-row = fast axis of P's A-layout.
__global__ __launch_bounds__(256) void k_attn(const short* __restrict__ Q,
                                              const short* __restrict__ Km,
                                              const short* __restrict__ Vt,
                                              const int* __restrict__ mask,
                                              short* __restrict__ Out) {
  __shared__ __attribute__((aligned(16))) short Qs[8192];  // 128x64, k-major planes
  __shared__ __attribute__((aligned(16))) short Ks[4096];  // 64x64, planes
  __shared__ __attribute__((aligned(16))) short Vs[4096];  // Vt: rows=d, cols=keys
  __shared__ __attribute__((aligned(16))) short Ps[8448];  // per-wave 8 planes x (32*8+8)
  __shared__ __attribute__((aligned(16))) float mk[64];

  const int tid = threadIdx.x;
  const int w = tid >> 6, lane = tid & 63;
  const int quad = lane >> 4, m16 = lane & 15;
  const int qb = blockIdx.x, hb = blockIdx.y;
  const int b = hb >> 4, h = hb & 15;
  const int wb = w * 2112;

  const short* Qh = Q + hb * (kL * kHD) + qb * 128 * kHD;
  const short* Kh = Km + hb * (kL * kHD);
  const short* Vh = Vt + hb * (kL * kHD);

#pragma unroll
  for (int p = 0; p < 4; ++p) {
    int ci = p * 256 + tid;
    int r = ci & 127, kc = ci >> 7;
    load_lds16(Qh + r * 64 + kc * 8, &Qs[ci * 8]);
  }
  __syncthreads();
  bf16x8 qf[2][2];
#pragma unroll
  for (int i = 0; i < 2; ++i)
#pragma unroll
    for (int s = 0; s < 2; ++s)
      qf[i][s] = *reinterpret_cast<const bf16x8*>(
          &Qs[(s * 4 + quad) * 1024 + (w * 32 + i * 16 + m16) * 8]);

  f32x4 oacc[2][4] = {};
  float lpart[2][4] = {{0, 0, 0, 0}, {0, 0, 0, 0}};

  const int r6 = tid & 63, kc6 = tid >> 6;
  for (int kb = 0; kb < 32; ++kb) {
    int kbase = kb * 64;
    load_lds16(Kh + (kbase + r6) * 64 + kc6 * 8, &Ks[tid * 8]);
    load_lds16(Kh + (kbase + r6) * 64 + (kc6 + 4) * 8, &Ks[(256 + tid) * 8]);
    load_lds16(Vh + r6 * 2048 + kbase + kc6 * 8, &Vs[tid * 8]);
    load_lds16(Vh + r6 * 2048 + kbase + (kc6 + 4) * 8, &Vs[(256 + tid) * 8]);
    if (tid < 64)
      mk[tid] = (mask[b * kL + kbase + tid] != 0) ? -10.0f : -1.0e10f;
    __syncthreads();

    bf16x8 kf[4][2];
#pragma unroll
    for (int j = 0; j < 4; ++j)
#pragma unroll
      for (int s = 0; s < 2; ++s)
        kf[j][s] = *reinterpret_cast<const bf16x8*>(
            &Ks[(s * 4 + quad) * 512 + (j * 16 + m16) * 8]);

    // S^T tiles: ST[j][i], j = key-tile (rows), i = q-tile (cols).
    // Init with mask offset (per-row = per-key broadcast float4 from mk).
    f32x4 ST[4][2];
#pragma unroll
    for (int j = 0; j < 4; ++j) {
      float4 mj4 = *reinterpret_cast<const float4*>(&mk[j * 16 + quad * 4]);
      f32x4 init; init[0] = mj4.x; init[1] = mj4.y; init[2] = mj4.z; init[3] = mj4.w;
#pragma unroll
      for (int i = 0; i < 2; ++i) ST[j][i] = init;
    }
#pragma unroll
    for (int j = 0; j < 4; ++j)
#pragma unroll
      for (int i = 0; i < 2; ++i) {
        ST[j][i] = __builtin_amdgcn_mfma_f32_16x16x32_bf16(kf[j][0], qf[i][0], ST[j][i], 0, 0, 0);
        ST[j][i] = __builtin_amdgcn_mfma_f32_16x16x32_bf16(kf[j][1], qf[i][1], ST[j][i], 0, 0, 0);
      }

    // Softmax numerator + pack to bf16 + b64 spill into P (A-operand layout).
    const int kc_w = (quad >> 1);   // within j: plane = j*2 + (quad>>1)
    const int inner = (quad & 1) * 4;
#pragma unroll
    for (int j = 0; j < 4; ++j)
#pragma unroll
      for (int i = 0; i < 2; ++i) {
        float p0 = __builtin_amdgcn_exp2f(ST[j][i][0]);
        float p1 = __builtin_amdgcn_exp2f(ST[j][i][1]);
        float p2 = __builtin_amdgcn_exp2f(ST[j][i][2]);
        float p3 = __builtin_amdgcn_exp2f(ST[j][i][3]);
        lpart[i][0] += p0; lpart[i][1] += p1;
        lpart[i][2] += p2; lpart[i][3] += p3;
        unsigned u0 = __builtin_bit_cast(unsigned, p0) + 0x8000u;
        unsigned u1 = __builtin_bit_cast(unsigned, p1) + 0x8000u;
        unsigned u2 = __builtin_bit_cast(unsigned, p2) + 0x8000u;
        unsigned u3 = __builtin_bit_cast(unsigned, p3) + 0x8000u;
        uint2 pk;
        pk.x = __builtin_amdgcn_perm(u1, u0, 0x07060302u);
        pk.y = __builtin_amdgcn_perm(u3, u2, 0x07060302u);
        *reinterpret_cast<uint2*>(
            &Ps[wb + (j * 2 + kc_w) * 264 + (i * 16 + m16) * 8 + inner]) = pk;
      }
    asm volatile("s_waitcnt lgkmcnt(0)" ::: "memory");  // own-wave P RAW

    bf16x8 pf[2][2], vf[4][2];
#pragma unroll
    for (int i = 0; i < 2; ++i)
#pragma unroll
      for (int s = 0; s < 2; ++s)
        pf[i][s] = *reinterpret_cast<const bf16x8*>(
            &Ps[wb + (s * 4 + quad) * 264 + (i * 16 + m16) * 8]);
#pragma unroll
    for (int j = 0; j < 4; ++j)
#pragma unroll
      for (int s = 0; s < 2; ++s)
        vf[j][s] = *reinterpret_cast<const bf16x8*>(
            &Vs[(s * 4 + quad) * 512 + (j * 16 + m16) * 8]);
#pragma unroll
    for (int i = 0; i < 2; ++i)
#pragma unroll
      for (int j = 0; j < 4; ++j) {
        oacc[i][j] = __builtin_amdgcn_mfma_f32_16x16x32_bf16(pf[i][0], vf[j][0], oacc[i][j], 0, 0, 0);
        oacc[i][j] = __builtin_amdgcn_mfma_f32_16x16x32_bf16(pf[i][1], vf[j][1], oacc[i][j], 0, 0, 0);
      }
    __syncthreads();
  }

  // l reduce: lane holds partials for q = i*16+m16 over keys {quad's 16}.
  float linv[2][4];
#pragma unroll
  for (int i = 0; i < 2; ++i) {
    float l = lpart[i][0] + lpart[i][1] + lpart[i][2] + lpart[i][3];
    l += __shfl_xor(l, 16);
    l += __shfl_xor(l, 32);  // now full l(q = i*16+m16)
#pragma unroll
    for (int rg = 0; rg < 4; ++rg)
      linv[i][rg] = 1.0f / __shfl(l, quad * 4 + rg);
  }

#pragma unroll
  for (int i = 0; i < 2; ++i)
#pragma unroll
    for (int j = 0; j < 4; ++j) {
      int d = j * 16 + m16;
#pragma unroll
      for (int rg = 0; rg < 4; ++rg) {
        int ql = qb * 128 + w * 32 + i * 16 + quad * 4 + rg;
        Out[(b * kL + ql) * kE + h * kHD + d] = f2bf(oacc[i][j][rg] * linv[i][rg]);
      }
    }
}

extern "C" void kernel_launch(void* const* d_in, const int* in_sizes, int n_in,
                              void* d_out, int out_size, void* d_ws, size_t ws_size,
                              hipStream_t stream) {
  const float* x  = (const float*)d_in[0];
  const int* mask = (const int*)d_in[1];
  const float* Wq = (const float*)d_in[2];
  const float* bq = (const float*)d_in[3];
  const float* Wk = (const float*)d_in[4];
  const float* bk = (const float*)d_in[5];
  const float* Wv = (const float*)d_in[6];
  const float* bv = (const float*)d_in[7];
  const float* Wo = (const float*)d_in[8];
  const float* bo = (const float*)d_in[9];

  short* ws  = (short*)d_ws;
  short* xb  = ws;                  // 8388608 shorts
  short* Wqb = xb  + 8388608;       // 4 x 1048576, contiguous
  short* Wkb = Wqb + 1048576;
  short* Wvb = Wkb + 1048576;
  short* Wob = Wvb + 1048576;
  short* Qb  = Wob + 1048576;       // 8388608 each
  short* Kb  = Qb  + 8388608;
  short* Vtb = Kb  + 8388608;
  short* AOb = Vtb + 8388608;       // doubles as Vl before attention runs

  k_cvt<<<8192, 256, 0, stream>>>(x, xb, 8388608);
  k_cvtw<<<4096, 256, 0, stream>>>(Wq, Wk, Wv, Wo, Wqb);

  // V row-major into AOb (dead until attention), then transpose into Vtb.
  k_gemm_qkv<<<dim3(24, 64), 256, 0, stream>>>(xb, Wqb, Wkb, Wvb, bq, bk, bv, Qb, Kb, AOb);
  k_trv<<<dim3(32, 64), 256, 0, stream>>>(AOb, Vtb);
  k_attn<<<dim3(16, 64), 256, 0, stream>>>(Qb, Kb, Vtb, mask, AOb);
  k_gemm_out<<<dim3(8, 64), 256, 0, stream>>>(AOb, Wob, bo, (float*)d_out);
}